// Round 9
// baseline (642.215 us; speedup 1.0000x reference)
//
#include <hip/hip_runtime.h>

typedef unsigned short u16;
typedef unsigned int u32;
typedef __attribute__((ext_vector_type(8))) __bf16 bf16x8;
typedef __attribute__((ext_vector_type(4))) float f32x4;
typedef __attribute__((ext_vector_type(2))) u32 u32x2;
typedef __attribute__((ext_vector_type(4))) u32 u32x4;

__device__ __forceinline__ u16 f2bf(float f) {
    u32 u = __float_as_uint(f);
    u = (u + 0x7FFFu + ((u >> 16) & 1u)) >> 16;
    return (u16)u;
}
__device__ __forceinline__ bf16x8 cvt2bf(f32x4 lo, f32x4 hi) {
    bf16x8 r;
    r[0] = (__bf16)lo[0]; r[1] = (__bf16)lo[1]; r[2] = (__bf16)lo[2]; r[3] = (__bf16)lo[3];
    r[4] = (__bf16)hi[0]; r[5] = (__bf16)hi[1]; r[6] = (__bf16)hi[2]; r[7] = (__bf16)hi[3];
    return r;
}
__device__ __forceinline__ bf16x8 load8f_bf(const float* p) {
    return cvt2bf(*(const f32x4*)p, *(const f32x4*)(p + 4));
}
__device__ __forceinline__ u32 pk2(float x, float y) {
    __bf16 bx = (__bf16)x, by = (__bf16)y;
    return (u32)__builtin_bit_cast(u16, bx) | ((u32)__builtin_bit_cast(u16, by) << 16);
}

// packed A-fragment (W^T) layout, per layer: idx = ((s*4 + m)*64 + lane)*8 + j
// value = W[k][16*m + (lane&15)], k = s*32 + (lane>>4)*8 + j
#define PK_EW1 0
#define PK_EW2 12288
#define PK_EW3 16384
#define PK_NW1 20480
#define PK_NW2 28672
#define PK_NW3 32768
#define PK_TOTAL 36864
#define EW_U16 20480

__global__ void pack_weights_kernel(const float* __restrict__ eW1, const float* __restrict__ eW2,
                                    const float* __restrict__ eW3, const float* __restrict__ nW1,
                                    const float* __restrict__ nW2, const float* __restrict__ nW3,
                                    u16* __restrict__ P) {
    int idx = blockIdx.x * blockDim.x + threadIdx.x;
    if (idx >= PK_TOTAL) return;
    const float* W; int base;
    if (idx < PK_EW2)      { W = eW1; base = PK_EW1; }
    else if (idx < PK_EW3) { W = eW2; base = PK_EW2; }
    else if (idx < PK_NW1) { W = eW3; base = PK_EW3; }
    else if (idx < PK_NW2) { W = nW1; base = PK_NW1; }
    else if (idx < PK_NW3) { W = nW2; base = PK_NW2; }
    else                   { W = nW3; base = PK_NW3; }
    int r = idx - base;
    int j = r & 7, lane = (r >> 3) & 63, m = (r >> 9) & 3, s = r >> 11;
    int k = s * 32 + (lane >> 4) * 8 + j;
    int col = 16 * m + (lane & 15);
    P[idx] = f2bf(W[k * 64 + col]);
}

// ---------------- CSR build ----------------
__global__ void degree_kernel(const int* __restrict__ edge_idx, int* __restrict__ deg, int E) {
    int e = blockIdx.x * blockDim.x + threadIdx.x;
    if (e < E) atomicAdd(&deg[edge_idx[2 * e]], 1);
}

__global__ void scan_blocks_kernel(const int* __restrict__ deg, int* __restrict__ off,
                                   int* __restrict__ partials, int N) {
    __shared__ int sh[256];
    const int t = threadIdx.x;
    const int g = blockIdx.x * 256 + t;
    int v = (g < N) ? deg[g] : 0;
    sh[t] = v;
    __syncthreads();
#pragma unroll
    for (int d = 1; d < 256; d <<= 1) {
        int add = (t >= d) ? sh[t - d] : 0;
        __syncthreads();
        sh[t] += add;
        __syncthreads();
    }
    if (g < N) off[g] = sh[t] - v;
    if (t == 255) partials[blockIdx.x] = sh[255];
}

__global__ void scan_partials_kernel(int* __restrict__ partials, int nparts) {
    __shared__ int sh[256];
    const int t = threadIdx.x;
    int v = (t < nparts) ? partials[t] : 0;
    sh[t] = v;
    __syncthreads();
#pragma unroll
    for (int d = 1; d < 256; d <<= 1) {
        int add = (t >= d) ? sh[t - d] : 0;
        __syncthreads();
        sh[t] += add;
        __syncthreads();
    }
    if (t < nparts) partials[t] = sh[t] - v;
}

__global__ void finalize_offsets_kernel(int* __restrict__ off, int* __restrict__ pos,
                                        const int* __restrict__ partials, int N, int E) {
    int g = blockIdx.x * blockDim.x + threadIdx.x;
    if (g < N) {
        int o = off[g] + partials[g >> 8];
        off[g] = o;
        pos[g] = o;
    }
    if (g == 0) off[N] = E;
}

__global__ void fill_csr_kernel(const int* __restrict__ edge_idx, int* __restrict__ pos,
                                int* __restrict__ csr, int* __restrict__ rank, int E) {
    int e = blockIdx.x * blockDim.x + threadIdx.x;
    if (e < E) {
        int slot = atomicAdd(&pos[edge_idx[2 * e]], 1);
        csr[slot] = e;
        rank[e] = slot;
    }
}

// ---------------- gather (sorted path): linear read of slot-ordered bf16 rows ----------------
__global__ __launch_bounds__(256) void gather_sorted_kernel(
    const u16* __restrict__ sorted16, const int* __restrict__ off,
    u16* __restrict__ nodal16, int N)
{
    const int wid = threadIdx.x >> 6, lane = threadIdx.x & 63;
    const int n = blockIdx.x * 4 + wid;
    if (n >= N) return;
    const int g = lane >> 3;   // row-group 0..7
    const int c = lane & 7;    // 8-feat chunk 0..7
    const int beg = off[n], end = off[n + 1];
    float va[8], vb[8];
#pragma unroll
    for (int i = 0; i < 8; ++i) { va[i] = 0.0f; vb[i] = 0.0f; }
    int j = beg + g;
    for (; j + 8 < end; j += 16) {
        bf16x8 v1 = *(const bf16x8*)(sorted16 + (size_t)j * 64 + c * 8);
        bf16x8 v2 = *(const bf16x8*)(sorted16 + (size_t)(j + 8) * 64 + c * 8);
#pragma unroll
        for (int i = 0; i < 8; ++i) { va[i] += (float)v1[i]; vb[i] += (float)v2[i]; }
    }
    if (j < end) {
        bf16x8 v1 = *(const bf16x8*)(sorted16 + (size_t)j * 64 + c * 8);
#pragma unroll
        for (int i = 0; i < 8; ++i) va[i] += (float)v1[i];
    }
#pragma unroll
    for (int i = 0; i < 8; ++i) {
        va[i] += vb[i];
        va[i] += __shfl_xor(va[i], 8, 64);
        va[i] += __shfl_xor(va[i], 16, 64);
        va[i] += __shfl_xor(va[i], 32, 64);
    }
    if (g == 0) {
        u32x4 q;
        q[0] = pk2(va[0], va[1]); q[1] = pk2(va[2], va[3]);
        q[2] = pk2(va[4], va[5]); q[3] = pk2(va[6], va[7]);
        *(u32x4*)(nodal16 + (size_t)n * 64 + c * 8) = q;
    }
}

// ---------------- gather (fallback): csr-indexed random read of out_edge fp32 ----------------
__global__ __launch_bounds__(256) void gather_csr_kernel(
    const float* __restrict__ proc_edge, const int* __restrict__ off,
    const int* __restrict__ csr, u16* __restrict__ nodal16, int N)
{
    const int wid = threadIdx.x >> 6, lane = threadIdx.x & 63;
    const int n = blockIdx.x * 4 + wid;
    if (n >= N) return;
    const int r = lane >> 4;
    const int q = lane & 15;
    const int beg = off[n], end = off[n + 1];
    f32x4 v0 = 0.0f, v1 = 0.0f, v2 = 0.0f, v3 = 0.0f;
    int j = beg + r;
    for (; j + 12 < end; j += 16) {
        int e0 = csr[j], e1 = csr[j + 4], e2 = csr[j + 8], e3 = csr[j + 12];
        v0 += *(const f32x4*)(proc_edge + (size_t)e0 * 64 + q * 4);
        v1 += *(const f32x4*)(proc_edge + (size_t)e1 * 64 + q * 4);
        v2 += *(const f32x4*)(proc_edge + (size_t)e2 * 64 + q * 4);
        v3 += *(const f32x4*)(proc_edge + (size_t)e3 * 64 + q * 4);
    }
    for (; j < end; j += 4) {
        int e0 = csr[j];
        v0 += *(const f32x4*)(proc_edge + (size_t)e0 * 64 + q * 4);
    }
    v0 += v1; v2 += v3; v0 += v2;
#pragma unroll
    for (int i = 0; i < 4; ++i) {
        v0[i] += __shfl_xor(v0[i], 16, 64);
        v0[i] += __shfl_xor(v0[i], 32, 64);
    }
    if (r == 0) {
        u32x2 pv; pv[0] = pk2(v0[0], v0[1]); pv[1] = pk2(v0[2], v0[3]);
        *(u32x2*)(nodal16 + (size_t)n * 64 + q * 4) = pv;
    }
}

// ---------------- edge MLP + LN: natural order, 24-load batch, 40KB weight LDS ----------------
#define ET 2
__global__ __launch_bounds__(512, 4) void edge_mlp_kernel(
    const float* __restrict__ node_feat, const float* __restrict__ edge_feat,
    const int* __restrict__ edge_idx, const int* __restrict__ rank,
    const u16* __restrict__ Pw,
    const float* __restrict__ b1g, const float* __restrict__ b2g, const float* __restrict__ b3g,
    const float* __restrict__ gg, const float* __restrict__ betag,
    float* __restrict__ out_edge, u16* __restrict__ sorted16, int E)
{
    __shared__ u16 wlds[EW_U16];    // 40 KB: EW1 | EW2 | EW3
    __shared__ u16 htile[8][1024];  // per-wave 16x64 bf16 tile, XOR-swizzled
    __shared__ float params[5][64];
    const int tid = threadIdx.x;
#pragma unroll
    for (int i = 0; i < 5; ++i) {
        int idx = i * 512 + tid;
        *(u32x4*)(wlds + (size_t)idx * 8) = *(const u32x4*)(Pw + (size_t)idx * 8);
    }
    if (tid < 64) {
        params[0][tid] = b1g[tid];
        params[1][tid] = b2g[tid];
        params[2][tid] = b3g[tid];
        params[3][tid] = gg[tid];
        params[4][tid] = betag[tid];
    }
    __syncthreads();

    const int wid = tid >> 6, lane = tid & 63;
    const int er = lane & 15, a = lane >> 4;
    const int ebase = (blockIdx.x * 8 + wid) * (16 * ET);
    u16* ht = htile[wid];
    const int swz = (er & 7) << 4;

    int eidx[ET], cn[ET], sn[ET], rk[ET];
#pragma unroll
    for (int t = 0; t < ET; ++t) {
        int e = ebase + t * 16 + er;
        if (e > E - 1) e = E - 1;
        eidx[t] = e;
        int2 ii = *(const int2*)(edge_idx + 2 * e);
        cn[t] = ii.x; sn[t] = ii.y;
        rk[t] = sorted16 ? rank[e] : 0;
    }

    // ---- layer 1: ALL 24 loads (both subtiles) issued before any MFMA
    f32x4 raw[ET][12];
#pragma unroll
    for (int t = 0; t < ET; ++t)
#pragma unroll
        for (int s = 0; s < 6; ++s) {
            const float* src;
            if (s < 2)      src = edge_feat + (size_t)eidx[t] * 64 + s * 32 + a * 8;
            else if (s < 4) src = node_feat + (size_t)cn[t] * 64 + (s - 2) * 32 + a * 8;
            else            src = node_feat + (size_t)sn[t] * 64 + (s - 4) * 32 + a * 8;
            raw[t][2 * s]     = *(const f32x4*)src;
            raw[t][2 * s + 1] = *(const f32x4*)(src + 4);
        }

    f32x4 acc[ET][4];
#pragma unroll
    for (int t = 0; t < ET; ++t)
#pragma unroll
        for (int m = 0; m < 4; ++m) acc[t][m] = 0.0f;
#pragma unroll
    for (int t = 0; t < ET; ++t)
#pragma unroll
        for (int s = 0; s < 6; ++s) {
            bf16x8 bf = cvt2bf(raw[t][2 * s], raw[t][2 * s + 1]);
#pragma unroll
            for (int m = 0; m < 4; ++m) {
                bf16x8 af = *(const bf16x8*)(wlds + PK_EW1 + ((s * 4 + m) * 64 + lane) * 8);
                acc[t][m] = __builtin_amdgcn_mfma_f32_16x16x32_bf16(af, bf, acc[t][m], 0, 0, 0);
            }
        }

    // ---- layers 2 & 3 per subtile (weights resident in LDS)
#pragma unroll
    for (int t = 0; t < ET; ++t) {
        // bias + relu (layer1) -> tile
#pragma unroll
        for (int m = 0; m < 4; ++m) {
            float v0 = fmaxf(acc[t][m][0] + params[0][16 * m + 4 * a + 0], 0.0f);
            float v1 = fmaxf(acc[t][m][1] + params[0][16 * m + 4 * a + 1], 0.0f);
            float v2 = fmaxf(acc[t][m][2] + params[0][16 * m + 4 * a + 2], 0.0f);
            float v3 = fmaxf(acc[t][m][3] + params[0][16 * m + 4 * a + 3], 0.0f);
            u32x2 pv; pv[0] = pk2(v0, v1); pv[1] = pk2(v2, v3);
            int boff = (er * 128 + (16 * m + 4 * a) * 2) ^ swz;
            *(u32x2*)((char*)ht + boff) = pv;
        }
        // layer 2: K = 64
        f32x4 a2[4];
#pragma unroll
        for (int m = 0; m < 4; ++m) a2[m] = 0.0f;
#pragma unroll
        for (int s = 0; s < 2; ++s) {
            int boff = (er * 128 + s * 64 + a * 16) ^ swz;
            bf16x8 bf = *(const bf16x8*)((char*)ht + boff);
#pragma unroll
            for (int m = 0; m < 4; ++m) {
                bf16x8 af = *(const bf16x8*)(wlds + PK_EW2 + ((s * 4 + m) * 64 + lane) * 8);
                a2[m] = __builtin_amdgcn_mfma_f32_16x16x32_bf16(af, bf, a2[m], 0, 0, 0);
            }
        }
        // bias + relu (layer2) -> tile
#pragma unroll
        for (int m = 0; m < 4; ++m) {
            float v0 = fmaxf(a2[m][0] + params[1][16 * m + 4 * a + 0], 0.0f);
            float v1 = fmaxf(a2[m][1] + params[1][16 * m + 4 * a + 1], 0.0f);
            float v2 = fmaxf(a2[m][2] + params[1][16 * m + 4 * a + 2], 0.0f);
            float v3 = fmaxf(a2[m][3] + params[1][16 * m + 4 * a + 3], 0.0f);
            u32x2 pv; pv[0] = pk2(v0, v1); pv[1] = pk2(v2, v3);
            int boff = (er * 128 + (16 * m + 4 * a) * 2) ^ swz;
            *(u32x2*)((char*)ht + boff) = pv;
        }
        // layer 3: K = 64 (no relu)
        f32x4 a3[4];
#pragma unroll
        for (int m = 0; m < 4; ++m) a3[m] = 0.0f;
#pragma unroll
        for (int s = 0; s < 2; ++s) {
            int boff = (er * 128 + s * 64 + a * 16) ^ swz;
            bf16x8 bf = *(const bf16x8*)((char*)ht + boff);
#pragma unroll
            for (int m = 0; m < 4; ++m) {
                bf16x8 af = *(const bf16x8*)(wlds + PK_EW3 + ((s * 4 + m) * 64 + lane) * 8);
                a3[m] = __builtin_amdgcn_mfma_f32_16x16x32_bf16(af, bf, a3[m], 0, 0, 0);
            }
        }
        // LayerNorm + stores
        float vals[16], sum = 0.0f, ssq = 0.0f;
#pragma unroll
        for (int m = 0; m < 4; ++m)
#pragma unroll
            for (int r = 0; r < 4; ++r) {
                float v = a3[m][r] + params[2][16 * m + 4 * a + r];
                vals[4 * m + r] = v; sum += v; ssq += v * v;
            }
        sum += __shfl_xor(sum, 16, 64); sum += __shfl_xor(sum, 32, 64);
        ssq += __shfl_xor(ssq, 16, 64); ssq += __shfl_xor(ssq, 32, 64);
        const float mean = sum * 0.015625f;
        const float var = ssq * 0.015625f - mean * mean;
        const float inv = rsqrtf(var + 1e-5f);
        const int e = ebase + t * 16 + er;
#pragma unroll
        for (int m = 0; m < 4; ++m) {
            f32x4 o;
#pragma unroll
            for (int r = 0; r < 4; ++r) {
                int f = 16 * m + 4 * a + r;
                o[r] = (vals[4 * m + r] - mean) * inv * params[3][f] + params[4][f];
            }
            if (e < E) {
                *(f32x4*)(out_edge + (size_t)e * 64 + 16 * m + 4 * a) = o;
                if (sorted16) {
                    u32x2 pv; pv[0] = pk2(o[0], o[1]); pv[1] = pk2(o[2], o[3]);
                    *(u32x2*)(sorted16 + (size_t)rk[t] * 64 + 16 * m + 4 * a) = pv;
                }
            }
        }
    }
}

// ---------------- node MLP + LN (nodal16 bf16; linear reads) ----------------
__global__ __launch_bounds__(256) void node_mlp_kernel(
    const float* __restrict__ node_feat, const u16* __restrict__ nodal16,
    const u16* __restrict__ Pw,
    const float* __restrict__ b1g, const float* __restrict__ b2g, const float* __restrict__ b3g,
    const float* __restrict__ gg, const float* __restrict__ betag,
    float* __restrict__ out_node, int N)
{
    __shared__ float params[5][64];
    __shared__ u16 htile[4][1024];
    const int tid = threadIdx.x;
    if (tid < 64) {
        params[0][tid] = b1g[tid];
        params[1][tid] = b2g[tid];
        params[2][tid] = b3g[tid];
        params[3][tid] = gg[tid];
        params[4][tid] = betag[tid];
    }
    __syncthreads();
    const int wid = tid >> 6, lane = tid & 63;
    const int er = lane & 15, a = lane >> 4;
    const int nbase = (blockIdx.x * 4 + wid) * 16;
    if (nbase >= N) return;
    const int n = nbase + er;
    u16* ht = htile[wid];
    const int swz = (er & 7) << 4;

    f32x4 acc[4];
#pragma unroll
    for (int m = 0; m < 4; ++m) acc[m] = 0.0f;

#pragma unroll
    for (int s = 0; s < 4; ++s) {
        bf16x8 af[4];
#pragma unroll
        for (int m = 0; m < 4; ++m)
            af[m] = *(const bf16x8*)(Pw + PK_NW1 + ((s * 4 + m) * 64 + lane) * 8);
        bf16x8 bf;
        if (s < 2) bf = load8f_bf(node_feat + (size_t)n * 64 + s * 32 + a * 8);
        else       bf = *(const bf16x8*)(nodal16 + (size_t)n * 64 + (s - 2) * 32 + a * 8);
#pragma unroll
        for (int m = 0; m < 4; ++m)
            acc[m] = __builtin_amdgcn_mfma_f32_16x16x32_bf16(af[m], bf, acc[m], 0, 0, 0);
    }
#pragma unroll
    for (int m = 0; m < 4; ++m) {
        float v0 = fmaxf(acc[m][0] + params[0][16 * m + 4 * a + 0], 0.0f);
        float v1 = fmaxf(acc[m][1] + params[0][16 * m + 4 * a + 1], 0.0f);
        float v2 = fmaxf(acc[m][2] + params[0][16 * m + 4 * a + 2], 0.0f);
        float v3 = fmaxf(acc[m][3] + params[0][16 * m + 4 * a + 3], 0.0f);
        u32x2 pv; pv[0] = pk2(v0, v1); pv[1] = pk2(v2, v3);
        int boff = (er * 128 + (16 * m + 4 * a) * 2) ^ swz;
        *(u32x2*)((char*)ht + boff) = pv;
    }

#pragma unroll
    for (int m = 0; m < 4; ++m) acc[m] = 0.0f;
#pragma unroll
    for (int s = 0; s < 2; ++s) {
        bf16x8 af[4];
#pragma unroll
        for (int m = 0; m < 4; ++m)
            af[m] = *(const bf16x8*)(Pw + PK_NW2 + ((s * 4 + m) * 64 + lane) * 8);
        int boff = (er * 128 + s * 64 + a * 16) ^ swz;
        bf16x8 bf = *(const bf16x8*)((char*)ht + boff);
#pragma unroll
        for (int m = 0; m < 4; ++m)
            acc[m] = __builtin_amdgcn_mfma_f32_16x16x32_bf16(af[m], bf, acc[m], 0, 0, 0);
    }
#pragma unroll
    for (int m = 0; m < 4; ++m) {
        float v0 = fmaxf(acc[m][0] + params[1][16 * m + 4 * a + 0], 0.0f);
        float v1 = fmaxf(acc[m][1] + params[1][16 * m + 4 * a + 1], 0.0f);
        float v2 = fmaxf(acc[m][2] + params[1][16 * m + 4 * a + 2], 0.0f);
        float v3 = fmaxf(acc[m][3] + params[1][16 * m + 4 * a + 3], 0.0f);
        u32x2 pv; pv[0] = pk2(v0, v1); pv[1] = pk2(v2, v3);
        int boff = (er * 128 + (16 * m + 4 * a) * 2) ^ swz;
        *(u32x2*)((char*)ht + boff) = pv;
    }

#pragma unroll
    for (int m = 0; m < 4; ++m) acc[m] = 0.0f;
#pragma unroll
    for (int s = 0; s < 2; ++s) {
        bf16x8 af[4];
#pragma unroll
        for (int m = 0; m < 4; ++m)
            af[m] = *(const bf16x8*)(Pw + PK_NW3 + ((s * 4 + m) * 64 + lane) * 8);
        int boff = (er * 128 + s * 64 + a * 16) ^ swz;
        bf16x8 bf = *(const bf16x8*)((char*)ht + boff);
#pragma unroll
        for (int m = 0; m < 4; ++m)
            acc[m] = __builtin_amdgcn_mfma_f32_16x16x32_bf16(af[m], bf, acc[m], 0, 0, 0);
    }
    float vals[16], sum = 0.0f, ssq = 0.0f;
#pragma unroll
    for (int m = 0; m < 4; ++m)
#pragma unroll
        for (int r = 0; r < 4; ++r) {
            float v = acc[m][r] + params[2][16 * m + 4 * a + r];
            vals[4 * m + r] = v; sum += v; ssq += v * v;
        }
    sum += __shfl_xor(sum, 16, 64); sum += __shfl_xor(sum, 32, 64);
    ssq += __shfl_xor(ssq, 16, 64); ssq += __shfl_xor(ssq, 32, 64);
    const float mean = sum * 0.015625f;
    const float var = ssq * 0.015625f - mean * mean;
    const float inv = rsqrtf(var + 1e-5f);
#pragma unroll
    for (int m = 0; m < 4; ++m) {
        f32x4 o;
#pragma unroll
        for (int r = 0; r < 4; ++r) {
            int f = 16 * m + 4 * a + r;
            o[r] = (vals[4 * m + r] - mean) * inv * params[3][f] + params[4][f];
        }
        *(f32x4*)(out_node + (size_t)n * 64 + 16 * m + 4 * a) = o;
    }
}

extern "C" void kernel_launch(void* const* d_in, const int* in_sizes, int n_in,
                              void* d_out, int out_size, void* d_ws, size_t ws_size,
                              hipStream_t stream) {
    const float* node_feat = (const float*)d_in[0];
    const float* edge_feat = (const float*)d_in[1];
    const int* edge_idx  = (const int*)d_in[2];
    const float* eW1 = (const float*)d_in[4];
    const float* eb1 = (const float*)d_in[5];
    const float* eW2 = (const float*)d_in[6];
    const float* eb2 = (const float*)d_in[7];
    const float* eW3 = (const float*)d_in[8];
    const float* eb3 = (const float*)d_in[9];
    const float* eg  = (const float*)d_in[10];
    const float* ebt = (const float*)d_in[11];
    const float* nW1 = (const float*)d_in[12];
    const float* nb1 = (const float*)d_in[13];
    const float* nW2 = (const float*)d_in[14];
    const float* nb2 = (const float*)d_in[15];
    const float* nW3 = (const float*)d_in[16];
    const float* nb3 = (const float*)d_in[17];
    const float* ng  = (const float*)d_in[18];
    const float* nbt = (const float*)d_in[19];

    const int N = in_sizes[0] / 64;
    const int E = in_sizes[1] / 64;
    const int nparts = (N + 255) / 256;

    // ws layout
    char* w0 = (char*)d_ws;
    char* w = w0;
    int* off      = (int*)w;                    w += (size_t)(N + 1) * 4;
    int* pos      = (int*)w;                    w += (size_t)N * 4;
    int* partials = (int*)w;                    w += 256 * 4;
    int* csr      = (int*)w;                    w += (size_t)E * 4;
    int* rank     = (int*)w;                    w += (size_t)E * 4;
    u16* Pw       = (u16*)w;                    w += (size_t)PK_TOTAL * 2;
    w = (char*)(((size_t)w + 255) & ~(size_t)255);
    u16* nodal16  = (u16*)w;                    w += (size_t)N * 64 * 2;
    w = (char*)(((size_t)w + 255) & ~(size_t)255);
    u16* sorted16 = (u16*)w;                    w += (size_t)E * 64 * 2;
    const bool use_sorted = ((size_t)(w - w0) <= ws_size);

    float* out_edge = (float*)d_out;
    float* out_node = out_edge + (size_t)E * 64;

    pack_weights_kernel<<<(PK_TOTAL + 255) / 256, 256, 0, stream>>>(eW1, eW2, eW3, nW1, nW2, nW3, Pw);

    // CSR build (pos doubles as degree histogram; rank = slot of each edge)
    hipMemsetAsync(pos, 0, (size_t)N * 4, stream);
    degree_kernel<<<(E + 255) / 256, 256, 0, stream>>>(edge_idx, pos, E);
    scan_blocks_kernel<<<nparts, 256, 0, stream>>>(pos, off, partials, N);
    scan_partials_kernel<<<1, 256, 0, stream>>>(partials, nparts);
    finalize_offsets_kernel<<<(N + 255) / 256, 256, 0, stream>>>(off, pos, partials, N, E);
    fill_csr_kernel<<<(E + 255) / 256, 256, 0, stream>>>(edge_idx, pos, csr, rank, E);

    // edge MLP (natural order, batched loads); also scatters bf16 rows to sorted16
    const int eblocks = (E + 255) / 256;
    edge_mlp_kernel<<<eblocks, 512, 0, stream>>>(node_feat, edge_feat, edge_idx, rank, Pw,
                                                 eb1, eb2, eb3, eg, ebt, out_edge,
                                                 use_sorted ? sorted16 : (u16*)nullptr, E);

    if (use_sorted)
        gather_sorted_kernel<<<(N + 3) / 4, 256, 0, stream>>>(sorted16, off, nodal16, N);
    else
        gather_csr_kernel<<<(N + 3) / 4, 256, 0, stream>>>(out_edge, off, csr, nodal16, N);

    const int nblocks = (N + 63) / 64;
    node_mlp_kernel<<<nblocks, 256, 0, stream>>>(node_feat, nodal16, Pw,
                                                 nb1, nb2, nb3, ng, nbt, out_node, N);
}

// Round 11
// 620.337 us; speedup vs baseline: 1.0353x; 1.0353x over previous
//
#include <hip/hip_runtime.h>

typedef unsigned short u16;
typedef unsigned int u32;
typedef __attribute__((ext_vector_type(8))) __bf16 bf16x8;
typedef __attribute__((ext_vector_type(4))) float f32x4;
typedef __attribute__((ext_vector_type(2))) u32 u32x2;
typedef __attribute__((ext_vector_type(4))) u32 u32x4;

__device__ __forceinline__ u16 f2bf(float f) {
    u32 u = __float_as_uint(f);
    u = (u + 0x7FFFu + ((u >> 16) & 1u)) >> 16;
    return (u16)u;
}
__device__ __forceinline__ bf16x8 cvt2bf(f32x4 lo, f32x4 hi) {
    bf16x8 r;
    r[0] = (__bf16)lo[0]; r[1] = (__bf16)lo[1]; r[2] = (__bf16)lo[2]; r[3] = (__bf16)lo[3];
    r[4] = (__bf16)hi[0]; r[5] = (__bf16)hi[1]; r[6] = (__bf16)hi[2]; r[7] = (__bf16)hi[3];
    return r;
}
__device__ __forceinline__ bf16x8 load8f_bf(const float* p) {
    return cvt2bf(*(const f32x4*)p, *(const f32x4*)(p + 4));
}
__device__ __forceinline__ u32 pk2(float x, float y) {
    __bf16 bx = (__bf16)x, by = (__bf16)y;
    return (u32)__builtin_bit_cast(u16, bx) | ((u32)__builtin_bit_cast(u16, by) << 16);
}

// packed A-fragment (W^T) layout, per layer: idx = ((s*4 + m)*64 + lane)*8 + j
// value = W[k][16*m + (lane&15)], k = s*32 + (lane>>4)*8 + j
#define PK_EW1 0
#define PK_EW2 12288
#define PK_EW3 16384
#define PK_NW1 20480
#define PK_NW2 28672
#define PK_NW3 32768
#define PK_TOTAL 36864

__global__ void pack_weights_kernel(const float* __restrict__ eW1, const float* __restrict__ eW2,
                                    const float* __restrict__ eW3, const float* __restrict__ nW1,
                                    const float* __restrict__ nW2, const float* __restrict__ nW3,
                                    u16* __restrict__ P) {
    int idx = blockIdx.x * blockDim.x + threadIdx.x;
    if (idx >= PK_TOTAL) return;
    const float* W; int base;
    if (idx < PK_EW2)      { W = eW1; base = PK_EW1; }
    else if (idx < PK_EW3) { W = eW2; base = PK_EW2; }
    else if (idx < PK_NW1) { W = eW3; base = PK_EW3; }
    else if (idx < PK_NW2) { W = nW1; base = PK_NW1; }
    else if (idx < PK_NW3) { W = nW2; base = PK_NW2; }
    else                   { W = nW3; base = PK_NW3; }
    int r = idx - base;
    int j = r & 7, lane = (r >> 3) & 63, m = (r >> 9) & 3, s = r >> 11;
    int k = s * 32 + (lane >> 4) * 8 + j;
    int col = 16 * m + (lane & 15);
    P[idx] = f2bf(W[k * 64 + col]);
}

// ---------------- CSR build ----------------
__global__ void degree_kernel(const int* __restrict__ edge_idx, int* __restrict__ deg, int E) {
    int e = blockIdx.x * blockDim.x + threadIdx.x;
    if (e < E) atomicAdd(&deg[edge_idx[2 * e]], 1);
}

__global__ void scan_blocks_kernel(const int* __restrict__ deg, int* __restrict__ off,
                                   int* __restrict__ partials, int N) {
    __shared__ int sh[256];
    const int t = threadIdx.x;
    const int g = blockIdx.x * 256 + t;
    int v = (g < N) ? deg[g] : 0;
    sh[t] = v;
    __syncthreads();
#pragma unroll
    for (int d = 1; d < 256; d <<= 1) {
        int add = (t >= d) ? sh[t - d] : 0;
        __syncthreads();
        sh[t] += add;
        __syncthreads();
    }
    if (g < N) off[g] = sh[t] - v;
    if (t == 255) partials[blockIdx.x] = sh[255];
}

__global__ void scan_partials_kernel(int* __restrict__ partials, int nparts) {
    __shared__ int sh[256];
    const int t = threadIdx.x;
    int v = (t < nparts) ? partials[t] : 0;
    sh[t] = v;
    __syncthreads();
#pragma unroll
    for (int d = 1; d < 256; d <<= 1) {
        int add = (t >= d) ? sh[t - d] : 0;
        __syncthreads();
        sh[t] += add;
        __syncthreads();
    }
    if (t < nparts) partials[t] = sh[t] - v;
}

__global__ void finalize_offsets_kernel(int* __restrict__ off, int* __restrict__ pos,
                                        const int* __restrict__ partials, int N, int E) {
    int g = blockIdx.x * blockDim.x + threadIdx.x;
    if (g < N) {
        int o = off[g] + partials[g >> 8];
        off[g] = o;
        pos[g] = o;
    }
    if (g == 0) off[N] = E;
}

__global__ void fill_csr_kernel(const int* __restrict__ edge_idx, int* __restrict__ pos,
                                int* __restrict__ csr, int E) {
    int e = blockIdx.x * blockDim.x + threadIdx.x;
    if (e < E) {
        int slot = atomicAdd(&pos[edge_idx[2 * e]], 1);
        csr[slot] = e;
    }
}

// ---------------- gather from bf16 edge rows (8 lanes per 128B row) ----------------
__global__ __launch_bounds__(256) void gather16_kernel(
    const u16* __restrict__ edge16, const int* __restrict__ off,
    const int* __restrict__ csr, u16* __restrict__ nodal16, int N)
{
    const int wid = threadIdx.x >> 6, lane = threadIdx.x & 63;
    const int n = blockIdx.x * 4 + wid;
    if (n >= N) return;
    const int g = lane >> 3;   // row-group 0..7
    const int c = lane & 7;    // 8-feat (16B) chunk
    const int beg = off[n], end = off[n + 1];
    float va[8], vb[8];
#pragma unroll
    for (int i = 0; i < 8; ++i) { va[i] = 0.0f; vb[i] = 0.0f; }
    int j = beg + g;
    for (; j + 8 < end; j += 16) {
        int e0 = csr[j], e1 = csr[j + 8];
        bf16x8 v1 = *(const bf16x8*)(edge16 + (size_t)e0 * 64 + c * 8);
        bf16x8 v2 = *(const bf16x8*)(edge16 + (size_t)e1 * 64 + c * 8);
#pragma unroll
        for (int i = 0; i < 8; ++i) { va[i] += (float)v1[i]; vb[i] += (float)v2[i]; }
    }
    for (; j < end; j += 8) {
        int e0 = csr[j];
        bf16x8 v1 = *(const bf16x8*)(edge16 + (size_t)e0 * 64 + c * 8);
#pragma unroll
        for (int i = 0; i < 8; ++i) va[i] += (float)v1[i];
    }
#pragma unroll
    for (int i = 0; i < 8; ++i) {
        va[i] += vb[i];
        va[i] += __shfl_xor(va[i], 8, 64);
        va[i] += __shfl_xor(va[i], 16, 64);
        va[i] += __shfl_xor(va[i], 32, 64);
    }
    if (g == 0) {
        u32x4 q;
        q[0] = pk2(va[0], va[1]); q[1] = pk2(va[2], va[3]);
        q[2] = pk2(va[4], va[5]); q[3] = pk2(va[6], va[7]);
        *(u32x4*)(nodal16 + (size_t)n * 64 + c * 8) = q;
    }
}

// fallback gather (fp32 out_edge) if ws can't hold edge16 — R7's proven kernel
__global__ __launch_bounds__(256) void gather_csr_kernel(
    const float* __restrict__ proc_edge, const int* __restrict__ off,
    const int* __restrict__ csr, u16* __restrict__ nodal16, int N)
{
    const int wid = threadIdx.x >> 6, lane = threadIdx.x & 63;
    const int n = blockIdx.x * 4 + wid;
    if (n >= N) return;
    const int r = lane >> 4;
    const int q = lane & 15;
    const int beg = off[n], end = off[n + 1];
    f32x4 v0 = 0.0f, v1 = 0.0f;
    int j = beg + r;
    for (; j + 4 < end; j += 8) {
        int e0 = csr[j], e1 = csr[j + 4];
        v0 += *(const f32x4*)(proc_edge + (size_t)e0 * 64 + q * 4);
        v1 += *(const f32x4*)(proc_edge + (size_t)e1 * 64 + q * 4);
    }
    if (j < end) v0 += *(const f32x4*)(proc_edge + (size_t)csr[j] * 64 + q * 4);
    v0 += v1;
#pragma unroll
    for (int i = 0; i < 4; ++i) {
        v0[i] += __shfl_xor(v0[i], 16, 64);
        v0[i] += __shfl_xor(v0[i], 32, 64);
    }
    if (r == 0) {
        u32x2 pv; pv[0] = pk2(v0[0], v0[1]); pv[1] = pk2(v0[2], v0[3]);
        *(u32x2*)(nodal16 + (size_t)n * 64 + q * 4) = pv;
    }
}

// ---------------- edge MLP + LN: R7 verbatim + guarded bf16 row copy ----------------
#define ET 2
__global__ __launch_bounds__(512, 6) void edge_mlp_kernel(
    const float* __restrict__ node_feat, const float* __restrict__ edge_feat,
    const int* __restrict__ edge_idx, const u16* __restrict__ Pw,
    const float* __restrict__ b1g, const float* __restrict__ b2g, const float* __restrict__ b3g,
    const float* __restrict__ gg, const float* __restrict__ betag,
    float* __restrict__ out_edge, u16* __restrict__ out_edge16, int E)
{
    __shared__ u16 wlds[12288];     // 24 KB: phase A = EW1; phase B = EW2|EW3
    __shared__ u16 htile[8][1024];  // per-wave 16x64 bf16 tile, XOR-swizzled
    __shared__ float params[5][64];
    const int tid = threadIdx.x;
    // ---- stage layer-1 weights (24 KB)
#pragma unroll
    for (int i = 0; i < 3; ++i) {
        int idx = i * 512 + tid;
        *(u32x4*)(wlds + (size_t)idx * 8) = *(const u32x4*)(Pw + PK_EW1 + (size_t)idx * 8);
    }
    if (tid < 64) {
        params[0][tid] = b1g[tid];
        params[1][tid] = b2g[tid];
        params[2][tid] = b3g[tid];
        params[3][tid] = gg[tid];
        params[4][tid] = betag[tid];
    }
    __syncthreads();

    const int wid = tid >> 6, lane = tid & 63;
    const int er = lane & 15, a = lane >> 4;
    const int ebase = (blockIdx.x * 8 + wid) * (16 * ET);
    u16* ht = htile[wid];
    const int swz = (er & 7) << 4;

    int eidx[ET], cn[ET], sn[ET];
#pragma unroll
    for (int t = 0; t < ET; ++t) {
        int e = ebase + t * 16 + er;
        if (e > E - 1) e = E - 1;
        eidx[t] = e;
        int2 ii = *(const int2*)(edge_idx + 2 * e);
        cn[t] = ii.x; sn[t] = ii.y;
    }

    f32x4 acc[ET][4];
#pragma unroll
    for (int t = 0; t < ET; ++t)
#pragma unroll
        for (int m = 0; m < 4; ++m) acc[t][m] = 0.0f;

    // ---- layer 1: K = 192; all 12 B-loads of a subtile issued before use
#pragma unroll
    for (int t = 0; t < ET; ++t) {
        f32x4 raw[12];
#pragma unroll
        for (int s = 0; s < 6; ++s) {
            const float* src;
            if (s < 2)      src = edge_feat + (size_t)eidx[t] * 64 + s * 32 + a * 8;
            else if (s < 4) src = node_feat + (size_t)cn[t] * 64 + (s - 2) * 32 + a * 8;
            else            src = node_feat + (size_t)sn[t] * 64 + (s - 4) * 32 + a * 8;
            raw[2 * s]     = *(const f32x4*)src;
            raw[2 * s + 1] = *(const f32x4*)(src + 4);
        }
#pragma unroll
        for (int s = 0; s < 6; ++s) {
            bf16x8 bf = cvt2bf(raw[2 * s], raw[2 * s + 1]);
#pragma unroll
            for (int m = 0; m < 4; ++m) {
                bf16x8 af = *(const bf16x8*)(wlds + ((s * 4 + m) * 64 + lane) * 8);
                acc[t][m] = __builtin_amdgcn_mfma_f32_16x16x32_bf16(af, bf, acc[t][m], 0, 0, 0);
            }
        }
    }
    __syncthreads();   // everyone done with layer-1 weights
    // ---- re-stage: EW2 | EW3 (16 KB) into the same buffer
#pragma unroll
    for (int i = 0; i < 2; ++i) {
        int idx = i * 512 + tid;
        *(u32x4*)(wlds + (size_t)idx * 8) = *(const u32x4*)(Pw + PK_EW2 + (size_t)idx * 8);
    }
    __syncthreads();

    // ---- layers 2 & 3 per subtile (weights from LDS: L2 at 0, L3 at 4096)
#pragma unroll
    for (int t = 0; t < ET; ++t) {
        // bias + relu (layer1) -> tile
#pragma unroll
        for (int m = 0; m < 4; ++m) {
            float v0 = fmaxf(acc[t][m][0] + params[0][16 * m + 4 * a + 0], 0.0f);
            float v1 = fmaxf(acc[t][m][1] + params[0][16 * m + 4 * a + 1], 0.0f);
            float v2 = fmaxf(acc[t][m][2] + params[0][16 * m + 4 * a + 2], 0.0f);
            float v3 = fmaxf(acc[t][m][3] + params[0][16 * m + 4 * a + 3], 0.0f);
            u32x2 pv; pv[0] = pk2(v0, v1); pv[1] = pk2(v2, v3);
            int boff = (er * 128 + (16 * m + 4 * a) * 2) ^ swz;
            *(u32x2*)((char*)ht + boff) = pv;
        }
        // layer 2: K = 64
        f32x4 a2[4];
#pragma unroll
        for (int m = 0; m < 4; ++m) a2[m] = 0.0f;
#pragma unroll
        for (int s = 0; s < 2; ++s) {
            int boff = (er * 128 + s * 64 + a * 16) ^ swz;
            bf16x8 bf = *(const bf16x8*)((char*)ht + boff);
#pragma unroll
            for (int m = 0; m < 4; ++m) {
                bf16x8 af = *(const bf16x8*)(wlds + ((s * 4 + m) * 64 + lane) * 8);
                a2[m] = __builtin_amdgcn_mfma_f32_16x16x32_bf16(af, bf, a2[m], 0, 0, 0);
            }
        }
        // bias + relu (layer2) -> tile (same-wave DS ops are in-order)
#pragma unroll
        for (int m = 0; m < 4; ++m) {
            float v0 = fmaxf(a2[m][0] + params[1][16 * m + 4 * a + 0], 0.0f);
            float v1 = fmaxf(a2[m][1] + params[1][16 * m + 4 * a + 1], 0.0f);
            float v2 = fmaxf(a2[m][2] + params[1][16 * m + 4 * a + 2], 0.0f);
            float v3 = fmaxf(a2[m][3] + params[1][16 * m + 4 * a + 3], 0.0f);
            u32x2 pv; pv[0] = pk2(v0, v1); pv[1] = pk2(v2, v3);
            int boff = (er * 128 + (16 * m + 4 * a) * 2) ^ swz;
            *(u32x2*)((char*)ht + boff) = pv;
        }
        // layer 3: K = 64 (no relu)
        f32x4 a3[4];
#pragma unroll
        for (int m = 0; m < 4; ++m) a3[m] = 0.0f;
#pragma unroll
        for (int s = 0; s < 2; ++s) {
            int boff = (er * 128 + s * 64 + a * 16) ^ swz;
            bf16x8 bf = *(const bf16x8*)((char*)ht + boff);
#pragma unroll
            for (int m = 0; m < 4; ++m) {
                bf16x8 af = *(const bf16x8*)(wlds + 4096 + ((s * 4 + m) * 64 + lane) * 8);
                a3[m] = __builtin_amdgcn_mfma_f32_16x16x32_bf16(af, bf, a3[m], 0, 0, 0);
            }
        }
        // LayerNorm + stores (fp32 output + linear bf16 copy for the gather)
        float vals[16], sum = 0.0f, ssq = 0.0f;
#pragma unroll
        for (int m = 0; m < 4; ++m)
#pragma unroll
            for (int r = 0; r < 4; ++r) {
                float v = a3[m][r] + params[2][16 * m + 4 * a + r];
                vals[4 * m + r] = v; sum += v; ssq += v * v;
            }
        sum += __shfl_xor(sum, 16, 64); sum += __shfl_xor(sum, 32, 64);
        ssq += __shfl_xor(ssq, 16, 64); ssq += __shfl_xor(ssq, 32, 64);
        const float mean = sum * 0.015625f;
        const float var = ssq * 0.015625f - mean * mean;
        const float inv = rsqrtf(var + 1e-5f);
        const int e = ebase + t * 16 + er;
        if (e < E) {
#pragma unroll
            for (int m = 0; m < 4; ++m) {
                f32x4 o;
#pragma unroll
                for (int r = 0; r < 4; ++r) {
                    int f = 16 * m + 4 * a + r;
                    o[r] = (vals[4 * m + r] - mean) * inv * params[3][f] + params[4][f];
                }
                *(f32x4*)(out_edge + (size_t)e * 64 + 16 * m + 4 * a) = o;
                if (out_edge16) {
                    u32x2 pv; pv[0] = pk2(o[0], o[1]); pv[1] = pk2(o[2], o[3]);
                    *(u32x2*)(out_edge16 + (size_t)e * 64 + 16 * m + 4 * a) = pv;
                }
            }
        }
    }
}

// ---------------- node MLP + LN (nodal16 bf16; linear reads) — R7 verbatim ----------------
__global__ __launch_bounds__(256) void node_mlp_kernel(
    const float* __restrict__ node_feat, const u16* __restrict__ nodal16,
    const u16* __restrict__ Pw,
    const float* __restrict__ b1g, const float* __restrict__ b2g, const float* __restrict__ b3g,
    const float* __restrict__ gg, const float* __restrict__ betag,
    float* __restrict__ out_node, int N)
{
    __shared__ float params[5][64];
    __shared__ u16 htile[4][1024];
    const int tid = threadIdx.x;
    if (tid < 64) {
        params[0][tid] = b1g[tid];
        params[1][tid] = b2g[tid];
        params[2][tid] = b3g[tid];
        params[3][tid] = gg[tid];
        params[4][tid] = betag[tid];
    }
    __syncthreads();
    const int wid = tid >> 6, lane = tid & 63;
    const int er = lane & 15, a = lane >> 4;
    const int nbase = (blockIdx.x * 4 + wid) * 16;
    if (nbase >= N) return;
    const int n = nbase + er;
    u16* ht = htile[wid];
    const int swz = (er & 7) << 4;

    f32x4 acc[4];
#pragma unroll
    for (int m = 0; m < 4; ++m) acc[m] = 0.0f;

#pragma unroll
    for (int s = 0; s < 4; ++s) {
        bf16x8 af[4];
#pragma unroll
        for (int m = 0; m < 4; ++m)
            af[m] = *(const bf16x8*)(Pw + PK_NW1 + ((s * 4 + m) * 64 + lane) * 8);
        bf16x8 bf;
        if (s < 2) bf = load8f_bf(node_feat + (size_t)n * 64 + s * 32 + a * 8);
        else       bf = *(const bf16x8*)(nodal16 + (size_t)n * 64 + (s - 2) * 32 + a * 8);
#pragma unroll
        for (int m = 0; m < 4; ++m)
            acc[m] = __builtin_amdgcn_mfma_f32_16x16x32_bf16(af[m], bf, acc[m], 0, 0, 0);
    }
#pragma unroll
    for (int m = 0; m < 4; ++m) {
        float v0 = fmaxf(acc[m][0] + params[0][16 * m + 4 * a + 0], 0.0f);
        float v1 = fmaxf(acc[m][1] + params[0][16 * m + 4 * a + 1], 0.0f);
        float v2 = fmaxf(acc[m][2] + params[0][16 * m + 4 * a + 2], 0.0f);
        float v3 = fmaxf(acc[m][3] + params[0][16 * m + 4 * a + 3], 0.0f);
        u32x2 pv; pv[0] = pk2(v0, v1); pv[1] = pk2(v2, v3);
        int boff = (er * 128 + (16 * m + 4 * a) * 2) ^ swz;
        *(u32x2*)((char*)ht + boff) = pv;
    }

#pragma unroll
    for (int m = 0; m < 4; ++m) acc[m] = 0.0f;
#pragma unroll
    for (int s = 0; s < 2; ++s) {
        bf16x8 af[4];
#pragma unroll
        for (int m = 0; m < 4; ++m)
            af[m] = *(const bf16x8*)(Pw + PK_NW2 + ((s * 4 + m) * 64 + lane) * 8);
        int boff = (er * 128 + s * 64 + a * 16) ^ swz;
        bf16x8 bf = *(const bf16x8*)((char*)ht + boff);
#pragma unroll
        for (int m = 0; m < 4; ++m)
            acc[m] = __builtin_amdgcn_mfma_f32_16x16x32_bf16(af[m], bf, acc[m], 0, 0, 0);
    }
#pragma unroll
    for (int m = 0; m < 4; ++m) {
        float v0 = fmaxf(acc[m][0] + params[1][16 * m + 4 * a + 0], 0.0f);
        float v1 = fmaxf(acc[m][1] + params[1][16 * m + 4 * a + 1], 0.0f);
        float v2 = fmaxf(acc[m][2] + params[1][16 * m + 4 * a + 2], 0.0f);
        float v3 = fmaxf(acc[m][3] + params[1][16 * m + 4 * a + 3], 0.0f);
        u32x2 pv; pv[0] = pk2(v0, v1); pv[1] = pk2(v2, v3);
        int boff = (er * 128 + (16 * m + 4 * a) * 2) ^ swz;
        *(u32x2*)((char*)ht + boff) = pv;
    }

#pragma unroll
    for (int m = 0; m < 4; ++m) acc[m] = 0.0f;
#pragma unroll
    for (int s = 0; s < 2; ++s) {
        bf16x8 af[4];
#pragma unroll
        for (int m = 0; m < 4; ++m)
            af[m] = *(const bf16x8*)(Pw + PK_NW3 + ((s * 4 + m) * 64 + lane) * 8);
        int boff = (er * 128 + s * 64 + a * 16) ^ swz;
        bf16x8 bf = *(const bf16x8*)((char*)ht + boff);
#pragma unroll
        for (int m = 0; m < 4; ++m)
            acc[m] = __builtin_amdgcn_mfma_f32_16x16x32_bf16(af[m], bf, acc[m], 0, 0, 0);
    }
    float vals[16], sum = 0.0f, ssq = 0.0f;
#pragma unroll
    for (int m = 0; m < 4; ++m)
#pragma unroll
        for (int r = 0; r < 4; ++r) {
            float v = acc[m][r] + params[2][16 * m + 4 * a + r];
            vals[4 * m + r] = v; sum += v; ssq += v * v;
        }
    sum += __shfl_xor(sum, 16, 64); sum += __shfl_xor(sum, 32, 64);
    ssq += __shfl_xor(ssq, 16, 64); ssq += __shfl_xor(ssq, 32, 64);
    const float mean = sum * 0.015625f;
    const float var = ssq * 0.015625f - mean * mean;
    const float inv = rsqrtf(var + 1e-5f);
#pragma unroll
    for (int m = 0; m < 4; ++m) {
        f32x4 o;
#pragma unroll
        for (int r = 0; r < 4; ++r) {
            int f = 16 * m + 4 * a + r;
            o[r] = (vals[4 * m + r] - mean) * inv * params[3][f] + params[4][f];
        }
        *(f32x4*)(out_node + (size_t)n * 64 + 16 * m + 4 * a) = o;
    }
}

extern "C" void kernel_launch(void* const* d_in, const int* in_sizes, int n_in,
                              void* d_out, int out_size, void* d_ws, size_t ws_size,
                              hipStream_t stream) {
    const float* node_feat = (const float*)d_in[0];
    const float* edge_feat = (const float*)d_in[1];
    const int* edge_idx  = (const int*)d_in[2];
    const float* eW1 = (const float*)d_in[4];
    const float* eb1 = (const float*)d_in[5];
    const float* eW2 = (const float*)d_in[6];
    const float* eb2 = (const float*)d_in[7];
    const float* eW3 = (const float*)d_in[8];
    const float* eb3 = (const float*)d_in[9];
    const float* eg  = (const float*)d_in[10];
    const float* ebt = (const float*)d_in[11];
    const float* nW1 = (const float*)d_in[12];
    const float* nb1 = (const float*)d_in[13];
    const float* nW2 = (const float*)d_in[14];
    const float* nb2 = (const float*)d_in[15];
    const float* nW3 = (const float*)d_in[16];
    const float* nb3 = (const float*)d_in[17];
    const float* ng  = (const float*)d_in[18];
    const float* nbt = (const float*)d_in[19];

    const int N = in_sizes[0] / 64;
    const int E = in_sizes[1] / 64;
    const int nparts = (N + 255) / 256;

    // ws layout
    char* w0 = (char*)d_ws;
    char* w = w0;
    int* off      = (int*)w;                    w += (size_t)(N + 1) * 4;
    int* pos      = (int*)w;                    w += (size_t)N * 4;
    int* partials = (int*)w;                    w += 256 * 4;
    int* csr      = (int*)w;                    w += (size_t)E * 4;
    u16* Pw       = (u16*)w;                    w += (size_t)PK_TOTAL * 2;
    w = (char*)(((size_t)w + 255) & ~(size_t)255);
    u16* nodal16  = (u16*)w;                    w += (size_t)N * 64 * 2;
    w = (char*)(((size_t)w + 255) & ~(size_t)255);
    u16* edge16   = (u16*)w;                    w += (size_t)E * 64 * 2;
    const bool use16 = ((size_t)(w - w0) <= ws_size);

    float* out_edge = (float*)d_out;
    float* out_node = out_edge + (size_t)E * 64;

    pack_weights_kernel<<<(PK_TOTAL + 255) / 256, 256, 0, stream>>>(eW1, eW2, eW3, nW1, nW2, nW3, Pw);

    // edge MLP first (natural order, R7 structure); emits linear bf16 copy if ws allows
    const int eblocks = (E + 255) / 256;
    edge_mlp_kernel<<<eblocks, 512, 0, stream>>>(node_feat, edge_feat, edge_idx, Pw,
                                                 eb1, eb2, eb3, eg, ebt, out_edge,
                                                 use16 ? edge16 : (u16*)nullptr, E);

    // CSR build
    hipMemsetAsync(pos, 0, (size_t)N * 4, stream);
    degree_kernel<<<(E + 255) / 256, 256, 0, stream>>>(edge_idx, pos, E);
    scan_blocks_kernel<<<nparts, 256, 0, stream>>>(pos, off, partials, N);
    scan_partials_kernel<<<1, 256, 0, stream>>>(partials, nparts);
    finalize_offsets_kernel<<<(N + 255) / 256, 256, 0, stream>>>(off, pos, partials, N, E);
    fill_csr_kernel<<<(E + 255) / 256, 256, 0, stream>>>(edge_idx, pos, csr, E);

    if (use16)
        gather16_kernel<<<(N + 3) / 4, 256, 0, stream>>>(edge16, off, csr, nodal16, N);
    else
        gather_csr_kernel<<<(N + 3) / 4, 256, 0, stream>>>(out_edge, off, csr, nodal16, N);

    const int nblocks = (N + 63) / 64;
    node_mlp_kernel<<<nblocks, 256, 0, stream>>>(node_feat, nodal16, Pw,
                                                 nb1, nb2, nb3, ng, nbt, out_node, N);
}